// Round 4
// baseline (196.195 us; speedup 1.0000x reference)
//
#include <hip/hip_runtime.h>
#include <hip/hip_bf16.h>
#include <stdint.h>

// Problem constants (CZT_72533407694901)
#define MM   1840          // M (zoom bins)
#define M2   3680          // 2M rows of W / X
#define NN   512           // N time samples
#define K2   1024          // 2N columns of W
#define CS   8192          // C*S = 32*256
#define MPAD 3712          // 29 * 128 (GEMM row padding)

#define NB_M 29            // GEMM m-blocks (MPAD/128)
#define NB_N 64            // GEMM n-blocks (CS/128)

#define WPREP_BLOCKS (MPAD / 2)        // 1856 blocks, 2 rows each
#define XT_NB        (CS / 32)         // 256 n-tiles
#define XT_KB        (NN / 64)         // 8 k-tiles

typedef __bf16 bf16x8 __attribute__((ext_vector_type(8)));
typedef float  floatx4 __attribute__((ext_vector_type(4)));   // clang ext-vector:
                                                              // valid for nontemporal builtins

// -------------------------------------------------------------------------
// Kernel 1 (fused prep): block-index split between
//  (a) W-output assembly + A'' bf16 fold  (blocks [0, 1856))
//  (b) x transpose -> bf16 B^T            (blocks [1856, 1856+2048))
// -------------------------------------------------------------------------
__global__ __launch_bounds__(256) void czt_prep(const float* __restrict__ Wr,
                                                const float* __restrict__ Wi,
                                                const float* __restrict__ ac,
                                                const float* __restrict__ as_,
                                                const float* __restrict__ x,
                                                float* __restrict__ Wout,
                                                __hip_bfloat16* __restrict__ Abf,
                                                __hip_bfloat16* __restrict__ Bxt) {
    __shared__ float tile[64 * 33];     // transpose staging (pad 33: <=2-way, free)
    const int b   = blockIdx.x;
    const int tid = threadIdx.x;

    if (b < WPREP_BLOCKS) {
        // ---- (a) Wout row assembly + A'' fold: rows j = 2b, 2b+1 ----
        const int j = b * 2 + (tid >> 7);     // two rows per 256-thread block
        const int k = (tid & 127) * 4;        // 0..508, float4 per thread

        union { __hip_bfloat16 h[4]; uint2 u; } p;
        if (j < M2) {
            const int jj = (j < MM) ? j : j - MM;
            const floatx4 wr = *(const floatx4*)&Wr[(size_t)jj * NN + k];
            const floatx4 wi = *(const floatx4*)&Wi[(size_t)jj * NN + k];
            const floatx4 c  = *(const floatx4*)&ac[k];
            const floatx4 s  = *(const floatx4*)&as_[k];
            floatx4 f, g;         // Wout first half / second half
            floatx4 a;            // A'' values
            if (j < MM) {
                f = wr;
                g = -wi;
                a = wr * c - wi * s;
            } else {
                f = wi;
                g = wr;
                a = wi * c + wr * s;
            }
            // Hardtanh clamp (no-op on cos/sin, kept for fidelity)
#pragma unroll
            for (int e = 0; e < 4; ++e) {
                f[e] = fminf(1.f, fmaxf(-1.f, f[e]));
                g[e] = fminf(1.f, fmaxf(-1.f, g[e]));
            }
            // Wout is never re-read -> non-temporal, keep L2 for A''/B^T.
            __builtin_nontemporal_store(f, (floatx4*)&Wout[(size_t)j * K2 + k]);
            __builtin_nontemporal_store(g, (floatx4*)&Wout[(size_t)j * K2 + NN + k]);
            p.h[0] = __float2bfloat16(a[0]);
            p.h[1] = __float2bfloat16(a[1]);
            p.h[2] = __float2bfloat16(a[2]);
            p.h[3] = __float2bfloat16(a[3]);
        } else {
            p.h[0] = p.h[1] = p.h[2] = p.h[3] = __float2bfloat16(0.0f);
        }
        *(uint2*)&Abf[(size_t)j * NN + k] = p.u;
    } else {
        // ---- (b) transpose x [512 x 8192] fp32 -> Bxt bf16 [8192 x 512] ----
        const int tb = b - WPREP_BLOCKS;
        const int n0 = (tb & (XT_NB - 1)) * 32;   // 0..8160
        const int k0 = (tb >> 8) * 64;            // 0..448

        // load: 64 k-rows x 32 n-floats; thread = (row, 8-float chunk).
        // x is read exactly once -> non-temporal loads.
        const int row = tid >> 2;                  // 0..63
        const int c8  = (tid & 3) * 8;             // 0,8,16,24
        const floatx4* src = (const floatx4*)&x[(size_t)(k0 + row) * CS + n0 + c8];
        const floatx4 v0 = __builtin_nontemporal_load(src);
        const floatx4 v1 = __builtin_nontemporal_load(src + 1);
        float* tr = &tile[row * 33 + c8];
        tr[0] = v0[0]; tr[1] = v0[1]; tr[2] = v0[2]; tr[3] = v0[3];
        tr[4] = v1[0]; tr[5] = v1[1]; tr[6] = v1[2]; tr[7] = v1[3];
        __syncthreads();

        // store: thread = (n-row, k-octet); lanes 0..7 cover 128B contiguous
        const int oc = tid & 7;                    // k-octet 0..7
        const int nr = tid >> 3;                   // n 0..31
        union { __hip_bfloat16 h[8]; uint4 u; } q;
#pragma unroll
        for (int jj = 0; jj < 8; ++jj)
            q.h[jj] = __float2bfloat16(tile[(oc * 8 + jj) * 33 + nr]);
        *(uint4*)&Bxt[(size_t)(n0 + nr) * NN + k0 + oc * 8] = q.u;
    }
}

// -------------------------------------------------------------------------
// Kernel 2: GEMM  X[3680 x 8192] = A''[3680 x 512] * x[512 x 8192]
// 128x128 tile, BK=64, 4 waves, 16x16x32 bf16 MFMA, global_load_lds w=16.
// XCD-aware swizzle: xcd = b&7 owns an 8-wide n-slice (B-slice 1MB + A
// 3.8MB ~= 4.8MB working set per 4MB XCD-L2, vs 12.2MB unswizzled).
// X stores non-temporal: 120MB write-back must not evict A/B from L2.
// -------------------------------------------------------------------------
__device__ __forceinline__ void gload_lds16(const void* g, void* l) {
    __builtin_amdgcn_global_load_lds(
        (const __attribute__((address_space(1))) uint32_t*)g,
        (__attribute__((address_space(3))) uint32_t*)l,
        16, 0, 0);
}

__global__ __launch_bounds__(256) void czt_gemm(const __hip_bfloat16* __restrict__ Abf,
                                                const __hip_bfloat16* __restrict__ Bxt,
                                                float* __restrict__ Xout) {
    __shared__ __hip_bfloat16 As[128 * 64];   // [m in tile][k], stride 64
    __shared__ __hip_bfloat16 Bs[128 * 64];   // [n in tile][k], stride 64

    const int tid  = threadIdx.x;
    const int lane = tid & 63;
    const int w    = tid >> 6;        // wave 0..3
    const int quad = lane >> 4;       // 0..3
    const int r16  = lane & 15;

    // XCD-aware block swizzle (1856 = 8 XCDs x 8 n-blocks x 29 m-blocks)
    const int b    = blockIdx.x;
    const int xcd  = b & 7;
    const int i    = b >> 3;          // 0..231
    const int mb   = i % NB_M;        // 0..28
    const int nl   = i / NB_M;        // 0..7
    const int mtile = mb * 128;
    const int ntile = (xcd * 8 + nl) * 128;

    const int wm = (w >> 1) * 64;     // wave row offset in tile
    const int wn = (w & 1) * 64;      // wave col offset in tile

    // Staging: wave w loads tile rows [w*32, w*32+32), 4 issues of
    // 8 rows x 64 elements (1 KiB per wave-issue).
    const int rstage = w * 32 + (lane >> 3);   // row within tile
    const int cstage = (lane & 7) * 8;         // k element offset (16 B)
    const __hip_bfloat16* Ag = Abf + (size_t)(mtile + rstage) * NN + cstage;
    const __hip_bfloat16* Bg = Bxt + (size_t)(ntile + rstage) * NN + cstage;

    floatx4 acc[4][4] = {};

#pragma unroll
    for (int kt = 0; kt < NN / 64; ++kt) {
        __syncthreads();   // previous iter's LDS reads done before overwrite
#pragma unroll
        for (int t = 0; t < 4; ++t) {
            gload_lds16(Ag + (size_t)(t * 8) * NN + kt * 64, &As[(w * 32 + t * 8) * 64]);
            gload_lds16(Bg + (size_t)(t * 8) * NN + kt * 64, &Bs[(w * 32 + t * 8) * 64]);
        }
        __syncthreads();   // vmcnt(0) drain -> tiles visible

#pragma unroll
        for (int ks = 0; ks < 2; ++ks) {
            bf16x8 af[4], bfr[4];
#pragma unroll
            for (int i2 = 0; i2 < 4; ++i2) {
                af[i2]  = *(const bf16x8*)&As[(wm + i2 * 16 + r16) * 64 + ks * 32 + quad * 8];
                bfr[i2] = *(const bf16x8*)&Bs[(wn + i2 * 16 + r16) * 64 + ks * 32 + quad * 8];
            }
#pragma unroll
            for (int i2 = 0; i2 < 4; ++i2)
#pragma unroll
                for (int jn = 0; jn < 4; ++jn)
                    acc[i2][jn] = __builtin_amdgcn_mfma_f32_16x16x32_bf16(
                        af[i2], bfr[jn], acc[i2][jn], 0, 0, 0);
        }
    }

    // Epilogue: C/D layout col = lane&15, row = quad*4 + reg. Non-temporal.
#pragma unroll
    for (int i2 = 0; i2 < 4; ++i2) {
        const int rbase = mtile + wm + i2 * 16 + quad * 4;
#pragma unroll
        for (int rr = 0; rr < 4; ++rr) {
            const int rg = rbase + rr;
            if (rg < M2) {
#pragma unroll
                for (int jn = 0; jn < 4; ++jn) {
                    const int cg = ntile + wn + jn * 16 + r16;
                    __builtin_nontemporal_store(acc[i2][jn][rr],
                                                &Xout[(size_t)rg * CS + cg]);
                }
            }
        }
    }
}

// -------------------------------------------------------------------------
extern "C" void kernel_launch(void* const* d_in, const int* in_sizes, int n_in,
                              void* d_out, int out_size, void* d_ws, size_t ws_size,
                              hipStream_t stream) {
    const float* x   = (const float*)d_in[0];   // [512, 32, 256]
    const float* Wr  = (const float*)d_in[1];   // [1840, 512]
    const float* Wi  = (const float*)d_in[2];   // [1840, 512]
    const float* ac  = (const float*)d_in[3];   // [512]
    const float* as_ = (const float*)d_in[4];   // [512]

    float* Wout = (float*)d_out;                       // [3680, 1024]
    float* Xout = (float*)d_out + (size_t)M2 * K2;     // [3680, 8192]

    __hip_bfloat16* Abf = (__hip_bfloat16*)d_ws;                                  // [3712, 512]
    __hip_bfloat16* Bxt = (__hip_bfloat16*)((char*)d_ws + (size_t)MPAD * NN * 2); // [8192, 512]

    czt_prep<<<dim3(WPREP_BLOCKS + XT_NB * XT_KB), dim3(256), 0, stream>>>(
        Wr, Wi, ac, as_, x, Wout, Abf, Bxt);
    czt_gemm<<<dim3(NB_M * NB_N), dim3(256), 0, stream>>>(Abf, Bxt, Xout);
}

// Round 5
// 192.350 us; speedup vs baseline: 1.0200x; 1.0200x over previous
//
#include <hip/hip_runtime.h>
#include <hip/hip_bf16.h>
#include <stdint.h>

// Problem constants (CZT_72533407694901)
#define MM   1840          // M (zoom bins)
#define M2   3680          // 2M rows of W / X
#define NN   512           // N time samples
#define K2   1024          // 2N columns of W
#define CS   8192          // C*S = 32*256
#define MPAD 3712          // 29 * 128 (GEMM row padding)

#define NB_M 29            // GEMM m-blocks (MPAD/128)
#define NB_N 64            // GEMM n-blocks (CS/128)

#define WPREP_BLOCKS (MPAD / 2)        // 1856 blocks, 2 rows each
#define XT_NB        (CS / 32)         // 256 n-tiles
#define XT_KB        (NN / 64)         // 8 k-tiles

typedef __bf16 bf16x8 __attribute__((ext_vector_type(8)));
typedef float  floatx4 __attribute__((ext_vector_type(4)));   // clang ext-vector

// -------------------------------------------------------------------------
// Kernel 1 (fused prep): block-index split between
//  (a) W-output assembly + A'' bf16 fold  (blocks [0, 1856))
//  (b) x transpose -> bf16 B^T            (blocks [1856, 1856+2048))
// -------------------------------------------------------------------------
__global__ __launch_bounds__(256) void czt_prep(const float* __restrict__ Wr,
                                                const float* __restrict__ Wi,
                                                const float* __restrict__ ac,
                                                const float* __restrict__ as_,
                                                const float* __restrict__ x,
                                                float* __restrict__ Wout,
                                                __hip_bfloat16* __restrict__ Abf,
                                                __hip_bfloat16* __restrict__ Bxt) {
    __shared__ float tile[64 * 33];     // transpose staging (pad 33: <=2-way, free)
    const int b   = blockIdx.x;
    const int tid = threadIdx.x;

    if (b < WPREP_BLOCKS) {
        // ---- (a) Wout row assembly + A'' fold: rows j = 2b, 2b+1 ----
        const int j = b * 2 + (tid >> 7);     // two rows per 256-thread block
        const int k = (tid & 127) * 4;        // 0..508, float4 per thread

        union { __hip_bfloat16 h[4]; uint2 u; } p;
        if (j < M2) {
            const int jj = (j < MM) ? j : j - MM;
            const floatx4 wr = *(const floatx4*)&Wr[(size_t)jj * NN + k];
            const floatx4 wi = *(const floatx4*)&Wi[(size_t)jj * NN + k];
            const floatx4 c  = *(const floatx4*)&ac[k];
            const floatx4 s  = *(const floatx4*)&as_[k];
            floatx4 f, g;         // Wout first half / second half
            floatx4 a;            // A'' values
            if (j < MM) {
                f = wr;
                g = -wi;
                a = wr * c - wi * s;
            } else {
                f = wi;
                g = wr;
                a = wi * c + wr * s;
            }
            // Hardtanh clamp (no-op on cos/sin, kept for fidelity)
#pragma unroll
            for (int e = 0; e < 4; ++e) {
                f[e] = fminf(1.f, fmaxf(-1.f, f[e]));
                g[e] = fminf(1.f, fmaxf(-1.f, g[e]));
            }
            // Wout is never re-read -> non-temporal, keep L2 for A''/B^T.
            __builtin_nontemporal_store(f, (floatx4*)&Wout[(size_t)j * K2 + k]);
            __builtin_nontemporal_store(g, (floatx4*)&Wout[(size_t)j * K2 + NN + k]);
            p.h[0] = __float2bfloat16(a[0]);
            p.h[1] = __float2bfloat16(a[1]);
            p.h[2] = __float2bfloat16(a[2]);
            p.h[3] = __float2bfloat16(a[3]);
        } else {
            p.h[0] = p.h[1] = p.h[2] = p.h[3] = __float2bfloat16(0.0f);
        }
        *(uint2*)&Abf[(size_t)j * NN + k] = p.u;
    } else {
        // ---- (b) transpose x [512 x 8192] fp32 -> Bxt bf16 [8192 x 512] ----
        const int tb = b - WPREP_BLOCKS;
        const int n0 = (tb & (XT_NB - 1)) * 32;   // 0..8160
        const int k0 = (tb >> 8) * 64;            // 0..448

        // load: 64 k-rows x 32 n-floats; thread = (row, 8-float chunk).
        const int row = tid >> 2;                  // 0..63
        const int c8  = (tid & 3) * 8;             // 0,8,16,24
        const floatx4* src = (const floatx4*)&x[(size_t)(k0 + row) * CS + n0 + c8];
        const floatx4 v0 = __builtin_nontemporal_load(src);
        const floatx4 v1 = __builtin_nontemporal_load(src + 1);
        float* tr = &tile[row * 33 + c8];
        tr[0] = v0[0]; tr[1] = v0[1]; tr[2] = v0[2]; tr[3] = v0[3];
        tr[4] = v1[0]; tr[5] = v1[1]; tr[6] = v1[2]; tr[7] = v1[3];
        __syncthreads();

        // store: thread = (n-row, k-octet); lanes 0..7 cover 128B contiguous
        const int oc = tid & 7;                    // k-octet 0..7
        const int nr = tid >> 3;                   // n 0..31
        union { __hip_bfloat16 h[8]; uint4 u; } q;
#pragma unroll
        for (int jj = 0; jj < 8; ++jj)
            q.h[jj] = __float2bfloat16(tile[(oc * 8 + jj) * 33 + nr]);
        *(uint4*)&Bxt[(size_t)(n0 + nr) * NN + k0 + oc * 8] = q.u;
    }
}

// -------------------------------------------------------------------------
// Kernel 2: GEMM  X[3680 x 8192] = A''[3680 x 512] * x[512 x 8192]
// 128x128 tile, BK=64, 4 waves, 16x16x32 bf16 MFMA, global_load_lds w=16.
//
// XOR-swizzled LDS layout: with plain stride-64 rows, ds_read_b128 fragment
// loads have bank = f(ks,quad) only (row-independent) -> 16 lanes/quad on
// the same 4 banks (~2x serialization; cf. m98's SQ_LDS_BANK_CONFLICT).
// global_load_lds forces dest = base + lane*16, so we swizzle on the
// GLOBAL source side instead: lane l stages k-chunk (l&7)^((l>>3)&7) of its
// row (same 128B segment -> coalescing unchanged). LDS row r physical chunk
// p holds logical chunk p^(r&7); fragment reads fetch p = (ks*4+quad)^(r&7).
// XOR bijection -> every bank serves exactly 8 dwords/wave: conflict-free.
// -------------------------------------------------------------------------
__device__ __forceinline__ void gload_lds16(const void* g, void* l) {
    __builtin_amdgcn_global_load_lds(
        (const __attribute__((address_space(1))) uint32_t*)g,
        (__attribute__((address_space(3))) uint32_t*)l,
        16, 0, 0);
}

__global__ __launch_bounds__(256) void czt_gemm(const __hip_bfloat16* __restrict__ Abf,
                                                const __hip_bfloat16* __restrict__ Bxt,
                                                float* __restrict__ Xout) {
    __shared__ __hip_bfloat16 As[128 * 64];   // [m in tile][k-chunk swizzled]
    __shared__ __hip_bfloat16 Bs[128 * 64];   // [n in tile][k-chunk swizzled]

    const int tid  = threadIdx.x;
    const int lane = tid & 63;
    const int w    = tid >> 6;        // wave 0..3
    const int quad = lane >> 4;       // 0..3
    const int r16  = lane & 15;

    // XCD-aware block swizzle (1856 = 8 XCDs x 8 n-blocks x 29 m-blocks)
    const int b    = blockIdx.x;
    const int xcd  = b & 7;
    const int i    = b >> 3;          // 0..231
    const int mb   = i % NB_M;        // 0..28
    const int nl   = i / NB_M;        // 0..7
    const int mtile = mb * 128;
    const int ntile = (xcd * 8 + nl) * 128;

    const int wm = (w >> 1) * 64;     // wave row offset in tile
    const int wn = (w & 1) * 64;      // wave col offset in tile

    // Staging: wave w loads tile rows [w*32, w*32+32), 4 issues of
    // 8 rows x 64 elements (1 KiB per wave-issue). Source column is
    // XOR-swizzled by row%8 (see header comment).
    const int rsub   = lane >> 3;                        // 0..7 (row in 8-group)
    const int rstage = w * 32 + rsub;                    // row within tile
    const int cstage = ((lane & 7) ^ rsub) * 8;          // swizzled k offset
    const __hip_bfloat16* Ag = Abf + (size_t)(mtile + rstage) * NN + cstage;
    const __hip_bfloat16* Bg = Bxt + (size_t)(ntile + rstage) * NN + cstage;

    floatx4 acc[4][4] = {};

#pragma unroll
    for (int kt = 0; kt < NN / 64; ++kt) {
        __syncthreads();   // previous iter's LDS reads done before overwrite
#pragma unroll
        for (int t = 0; t < 4; ++t) {
            gload_lds16(Ag + (size_t)(t * 8) * NN + kt * 64, &As[(w * 32 + t * 8) * 64]);
            gload_lds16(Bg + (size_t)(t * 8) * NN + kt * 64, &Bs[(w * 32 + t * 8) * 64]);
        }
        __syncthreads();   // vmcnt(0) drain -> tiles visible

#pragma unroll
        for (int ks = 0; ks < 2; ++ks) {
            bf16x8 af[4], bfr[4];
#pragma unroll
            for (int i2 = 0; i2 < 4; ++i2) {
                const int ra = wm + i2 * 16 + r16;       // A row (ra&7 == r16&7)
                const int rb = wn + i2 * 16 + r16;       // B row
                const int pa = ((ks * 4 + quad) ^ (r16 & 7)) * 8;  // physical chunk
                af[i2]  = *(const bf16x8*)&As[ra * 64 + pa];
                bfr[i2] = *(const bf16x8*)&Bs[rb * 64 + pa];
            }
#pragma unroll
            for (int i2 = 0; i2 < 4; ++i2)
#pragma unroll
                for (int jn = 0; jn < 4; ++jn)
                    acc[i2][jn] = __builtin_amdgcn_mfma_f32_16x16x32_bf16(
                        af[i2], bfr[jn], acc[i2][jn], 0, 0, 0);
        }
    }

    // Epilogue: C/D layout col = lane&15, row = quad*4 + reg. Non-temporal.
#pragma unroll
    for (int i2 = 0; i2 < 4; ++i2) {
        const int rbase = mtile + wm + i2 * 16 + quad * 4;
#pragma unroll
        for (int rr = 0; rr < 4; ++rr) {
            const int rg = rbase + rr;
            if (rg < M2) {
#pragma unroll
                for (int jn = 0; jn < 4; ++jn) {
                    const int cg = ntile + wn + jn * 16 + r16;
                    __builtin_nontemporal_store(acc[i2][jn][rr],
                                                &Xout[(size_t)rg * CS + cg]);
                }
            }
        }
    }
}

// -------------------------------------------------------------------------
extern "C" void kernel_launch(void* const* d_in, const int* in_sizes, int n_in,
                              void* d_out, int out_size, void* d_ws, size_t ws_size,
                              hipStream_t stream) {
    const float* x   = (const float*)d_in[0];   // [512, 32, 256]
    const float* Wr  = (const float*)d_in[1];   // [1840, 512]
    const float* Wi  = (const float*)d_in[2];   // [1840, 512]
    const float* ac  = (const float*)d_in[3];   // [512]
    const float* as_ = (const float*)d_in[4];   // [512]

    float* Wout = (float*)d_out;                       // [3680, 1024]
    float* Xout = (float*)d_out + (size_t)M2 * K2;     // [3680, 8192]

    __hip_bfloat16* Abf = (__hip_bfloat16*)d_ws;                                  // [3712, 512]
    __hip_bfloat16* Bxt = (__hip_bfloat16*)((char*)d_ws + (size_t)MPAD * NN * 2); // [8192, 512]

    czt_prep<<<dim3(WPREP_BLOCKS + XT_NB * XT_KB), dim3(256), 0, stream>>>(
        Wr, Wi, ac, as_, x, Wout, Abf, Bxt);
    czt_gemm<<<dim3(NB_M * NB_N), dim3(256), 0, stream>>>(Abf, Bxt, Xout);
}